// Round 1
// baseline (791.467 us; speedup 1.0000x reference)
//
#include <hip/hip_runtime.h>

typedef _Float16 f16;
typedef f16 f16x8 __attribute__((ext_vector_type(8)));
typedef float f32x4 __attribute__((ext_vector_type(4)));

#define BATCH   32768
#define NF      162
#define ACCH    1024      // hidden accumulator width (without psqt)
#define KSL     192       // K padded to 192 halfs (6 x K=32 MFMA steps)
#define KSLOTS  24        // 16B slots per row (192/8)
#define NB      8
#define DIVQ    20
#define TM      64        // rows per block
#define NT      512       // threads per block
#define NCH     128       // hidden chunk
#define MAXBLK  (BATCH/TM + NB - 1)   // 519

// workspace layout (bytes)
#define WS_WACC16   0
#define WS_W116     (WS_WACC16 + ACCH*KSL*2)       // 393216
#define WS_BUCKET   (WS_W116 + 256*2048*2)         // 1441792
#define WS_ORDER    (WS_BUCKET + BATCH*4)          // 1572864
#define WS_CNT      (WS_ORDER + BATCH*4)           // 1703936
#define WS_BASE     (WS_CNT + 32)
#define WS_CURSOR   (WS_BASE + 32)

#define LDS_BYTES   115840

// ---------------- prep: convert weights to f16 (padded) ----------------
__global__ void k_prep(const float* __restrict__ Wacc, const float* __restrict__ W1,
                       f16* __restrict__ wacc16, f16* __restrict__ w116)
{
    int tid = blockIdx.x * blockDim.x + threadIdx.x;
    int stride = gridDim.x * blockDim.x;
    for (int t = tid; t < ACCH * KSL; t += stride) {
        int r = t / KSL, k = t - r * KSL;
        float v = (k < NF) ? Wacc[r * NF + k] : 0.f;
        wacc16[t] = (f16)v;
    }
    for (int t = tid; t < 256 * 2048; t += stride) {
        w116[t] = (f16)W1[t];
    }
}

// ---------------- binning: bucket per row + histogram ----------------
__global__ void k_bincount(const float* __restrict__ stm, int* __restrict__ bucket,
                           int* __restrict__ cnt)
{
    int gw = (blockIdx.x * blockDim.x + threadIdx.x) >> 6;  // one wave per row
    int ln = threadIdx.x & 63;
    if (gw >= BATCH) return;
    const float* row = stm + (long)gw * NF;
    float s = 0.f;
    for (int k = ln; k < NF; k += 64) s += row[k];
    for (int off = 32; off > 0; off >>= 1) s += __shfl_down(s, off);
    if (ln == 0) {
        int pc = (int)(s + 0.5f);
        int b = pc / DIVQ; if (b > NB - 1) b = NB - 1;
        bucket[gw] = b;
        atomicAdd(&cnt[b], 1);
    }
}

__global__ void k_binsetup(const int* __restrict__ cnt, int* __restrict__ base,
                           int* __restrict__ cursor)
{
    if (threadIdx.x == 0 && blockIdx.x == 0) {
        int acc = 0;
        for (int b = 0; b < NB; b++) { base[b] = acc; cursor[b] = acc; acc += cnt[b]; }
    }
}

__global__ void k_binscatter(const int* __restrict__ bucket, int* __restrict__ cursor,
                             int* __restrict__ order)
{
    int i = blockIdx.x * blockDim.x + threadIdx.x;
    if (i >= BATCH) return;
    int b = bucket[i];
    int pos = atomicAdd(&cursor[b], 1);
    order[pos] = i;
}

// ---------------- fused main kernel ----------------
__global__ __launch_bounds__(NT) void k_main(
    const float* __restrict__ stm, const float* __restrict__ nstm,
    const float* __restrict__ Wacc, const float* __restrict__ bacc,
    const float* __restrict__ b1, const float* __restrict__ W2,
    const float* __restrict__ b2, const float* __restrict__ W3,
    const float* __restrict__ b3,
    const f16* __restrict__ wacc16, const f16* __restrict__ w116,
    const int* __restrict__ cnt, const int* __restrict__ base,
    const int* __restrict__ order,
    float* __restrict__ out)
{
    // ---- block -> (bucket, tile) map (uniform per block) ----
    int bkt = -1, tile = 0, tacc = 0;
    for (int b = 0; b < NB; b++) {
        int tb = (cnt[b] + TM - 1) / TM;
        if (bkt < 0 && (int)blockIdx.x < tacc + tb) { bkt = b; tile = blockIdx.x - tacc; }
        tacc += tb;
    }
    if (bkt < 0) return;
    int rowbase = base[bkt] + tile * TM;
    int nrows = cnt[bkt] - tile * TM; if (nrows > TM) nrows = TM;

    extern __shared__ __align__(16) char lds_raw[];
    f16* Fs   = (f16*)lds_raw;            // [TM][KSL]   swizzled slots
    f16* Wc   = Fs  + TM * KSL;           // [NCH][KSL]  swizzled
    f16* Xb   = Wc  + NCH * KSL;          // [TM][NCH]   swizzled
    f16* W1c  = Xb  + TM * NCH;           // [32][NCH]   swizzled
    f16* h1s  = W1c + 32 * NCH;           // [TM][40]
    f16* h2s  = h1s + TM * 40;            // [TM][40]
    f16* W2c  = h2s + TM * 40;            // [32][40]
    float* baccs = (float*)(W2c + 32 * 40);  // [1024]
    float* psq   = baccs + ACCH;             // [TM]
    float* w3s   = psq + TM;                 // [32]
    int*   idxl  = (int*)(w3s + 32);         // [TM]

    int tid = threadIdx.x;
    int wv = tid >> 6, ln = tid & 63;
    int l15 = ln & 15, l4 = ln >> 4;

    if (tid < TM) {
        int rr = rowbase + tid;
        idxl[tid] = order[(tid < nrows) ? rr : rowbase];
        psq[tid] = 0.f;
    }
    for (int i = tid; i < ACCH; i += NT) baccs[i] = bacc[i];
    if (tid < 32) w3s[tid] = W3[bkt * 32 + tid];
    for (int t = tid; t < 32 * 32; t += NT) {
        int n = t >> 5, k = t & 31;
        W2c[n * 40 + k] = (f16)W2[(bkt * 32 + n) * 32 + k];
    }
    __syncthreads();

    // wave tile assignment
    int mq = wv >> 2;   // phase1: rows mq*32 + {0,16}
    int nq = wv & 3;    // phase1: cols nq*32 + {0,16}
    int mt = wv >> 1;   // phase2/3: M-tile 0..3
    int nh = wv & 1;    // phase2/3: N-half 0..1

    f32x4 h1acc; h1acc[0] = h1acc[1] = h1acc[2] = h1acc[3] = 0.f;

    const float* psqw = Wacc + (long)ACCH * NF;   // psqt weight row (fp32)

    for (int s = 0; s < 2; s++) {
        __syncthreads();  // Fs free
        const float* src = s ? nstm : stm;
        // ---- load feature tile (f16, zero-padded, slot-swizzled) ----
        for (int rr = 0; rr < TM / 8; rr++) {
            int r = wv * 8 + rr;
            const float* rp = src + (long)idxl[r] * NF;
            int x = r & 7;
            for (int k = ln; k < KSL; k += 64) {
                float v = (k < NF) ? rp[k] : 0.f;
                Fs[r * KSL + ((((k >> 3) ^ x) << 3) | (k & 7))] = (f16)v;
            }
        }
        __syncthreads();
        // ---- psqt partial (fp32 exact weights, f16 features are exact 0/1) ----
        if (tid < TM) {
            int r = tid, x = r & 7;
            float a = 0.f;
            for (int k = 0; k < NF; k++) {
                float fv = (float)Fs[r * KSL + ((((k >> 3) ^ x) << 3) | (k & 7))];
                a += fv * psqw[k];
            }
            psq[r] += s ? (-0.5f * a) : (0.5f * a);
        }

        for (int c = 0; c < ACCH / NCH; c++) {
            __syncthreads();  // Wc / W1c / Xb free (prev phase1+2 done)
            // ---- stage W_acc chunk ----
            for (int t = tid; t < NCH * KSLOTS; t += NT) {
                int n = t / KSLOTS, slot = t - n * KSLOTS;
                f16x8 v = *(const f16x8*)(wacc16 + (long)(c * NCH + n) * KSL + slot * 8);
                *(f16x8*)(Wc + n * KSL + ((slot ^ (n & 7)) << 3)) = v;
            }
            // ---- stage W1 chunk for (bucket, s, c) ----
            for (int t = tid; t < 32 * (NCH / 8); t += NT) {
                int n = t >> 4, slot = t & 15;
                f16x8 v = *(const f16x8*)(w116 + (long)(bkt * 32 + n) * 2048 + s * ACCH + c * NCH + slot * 8);
                *(f16x8*)(W1c + n * NCH + ((slot ^ (n & 7)) << 3)) = v;
            }
            __syncthreads();  // Wc, W1c ready

            // ---- phase 1: raw chunk = F @ Wacc_chunk^T, act -> Xb ----
            f32x4 accv[2][2];
            #pragma unroll
            for (int i = 0; i < 2; i++)
                #pragma unroll
                for (int j = 0; j < 2; j++)
                    accv[i][j][0] = accv[i][j][1] = accv[i][j][2] = accv[i][j][3] = 0.f;

            #pragma unroll
            for (int ks = 0; ks < KSL / 32; ks++) {
                int s0 = ks * 4 + l4;
                f16x8 af[2], bf[2];
                #pragma unroll
                for (int i = 0; i < 2; i++) {
                    int row = mq * 32 + i * 16 + l15;
                    af[i] = *(const f16x8*)(Fs + row * KSL + ((s0 ^ (row & 7)) << 3));
                    int nn = nq * 32 + i * 16 + l15;
                    bf[i] = *(const f16x8*)(Wc + nn * KSL + ((s0 ^ (nn & 7)) << 3));
                }
                #pragma unroll
                for (int i = 0; i < 2; i++)
                    #pragma unroll
                    for (int j = 0; j < 2; j++)
                        accv[i][j] = __builtin_amdgcn_mfma_f32_16x16x32_f16(af[i], bf[j], accv[i][j], 0, 0, 0);
            }
            // epilogue: bias + clip^2 -> Xb (f16, swizzled)
            #pragma unroll
            for (int i = 0; i < 2; i++)
                #pragma unroll
                for (int j = 0; j < 2; j++)
                    #pragma unroll
                    for (int jr = 0; jr < 4; jr++) {
                        int row = mq * 32 + i * 16 + l4 * 4 + jr;
                        int col = nq * 32 + j * 16 + l15;
                        float v = accv[i][j][jr] + baccs[c * NCH + col];
                        v = fminf(fmaxf(v, 0.f), 1.f);
                        v = v * v;
                        Xb[row * NCH + ((((col >> 3) ^ (row & 7)) << 3) | (col & 7))] = (f16)v;
                    }
            __syncthreads();  // Xb ready

            // ---- phase 2: h1 += act_chunk @ W1_chunk^T ----
            #pragma unroll
            for (int ks = 0; ks < NCH / 32; ks++) {
                int s0 = ks * 4 + l4;
                int row = mt * 16 + l15;
                f16x8 a = *(const f16x8*)(Xb + row * NCH + ((s0 ^ (row & 7)) << 3));
                int nn = nh * 16 + l15;
                f16x8 b = *(const f16x8*)(W1c + nn * NCH + ((s0 ^ (nn & 7)) << 3));
                h1acc = __builtin_amdgcn_mfma_f32_16x16x32_f16(a, b, h1acc, 0, 0, 0);
            }
        }
    }

    // ---- h1 finalize: bias + clip [0,1] ----
    #pragma unroll
    for (int jr = 0; jr < 4; jr++) {
        int row = mt * 16 + l4 * 4 + jr;
        int col = nh * 16 + l15;
        float v = h1acc[jr] + b1[bkt * 32 + col];
        v = fminf(fmaxf(v, 0.f), 1.f);
        h1s[row * 40 + col] = (f16)v;
    }
    __syncthreads();

    // ---- layer 3: h2 = clip(h1 @ W2_b^T + b2, 0, 1) ----
    {
        int row = mt * 16 + l15;
        f16x8 a = *(const f16x8*)(h1s + row * 40 + l4 * 8);
        int nn = nh * 16 + l15;
        f16x8 b = *(const f16x8*)(W2c + nn * 40 + l4 * 8);
        f32x4 acc; acc[0] = acc[1] = acc[2] = acc[3] = 0.f;
        acc = __builtin_amdgcn_mfma_f32_16x16x32_f16(a, b, acc, 0, 0, 0);
        #pragma unroll
        for (int jr = 0; jr < 4; jr++) {
            int r2 = mt * 16 + l4 * 4 + jr;
            int c2 = nh * 16 + l15;
            float v = acc[jr] + b2[bkt * 32 + c2];
            v = fminf(fmaxf(v, 0.f), 1.f);
            h2s[r2 * 40 + c2] = (f16)v;
        }
    }
    __syncthreads();

    // ---- layer 4 + psqt -> output ----
    if (tid < nrows) {
        float o = b3[bkt] + psq[tid];
        #pragma unroll 8
        for (int n = 0; n < 32; n++) o += (float)h2s[tid * 40 + n] * w3s[n];
        out[idxl[tid]] = o;
    }
}

// ---------------- launcher ----------------
extern "C" void kernel_launch(void* const* d_in, const int* in_sizes, int n_in,
                              void* d_out, int out_size, void* d_ws, size_t ws_size,
                              hipStream_t stream)
{
    (void)in_sizes; (void)n_in; (void)out_size; (void)ws_size;
    const float* stm  = (const float*)d_in[0];
    const float* nstm = (const float*)d_in[1];
    const float* Wacc = (const float*)d_in[2];
    const float* bacc = (const float*)d_in[3];
    const float* W1   = (const float*)d_in[4];
    const float* b1   = (const float*)d_in[5];
    const float* W2   = (const float*)d_in[6];
    const float* b2   = (const float*)d_in[7];
    const float* W3   = (const float*)d_in[8];
    const float* b3   = (const float*)d_in[9];
    float* out = (float*)d_out;

    char* ws = (char*)d_ws;
    f16* wacc16 = (f16*)(ws + WS_WACC16);
    f16* w116   = (f16*)(ws + WS_W116);
    int* bucket = (int*)(ws + WS_BUCKET);
    int* order  = (int*)(ws + WS_ORDER);
    int* cnt    = (int*)(ws + WS_CNT);
    int* basep  = (int*)(ws + WS_BASE);
    int* cursor = (int*)(ws + WS_CURSOR);

    hipMemsetAsync(cnt, 0, 32, stream);
    hipLaunchKernelGGL(k_prep, dim3(1024), dim3(256), 0, stream, Wacc, W1, wacc16, w116);
    hipLaunchKernelGGL(k_bincount, dim3(BATCH / 4), dim3(256), 0, stream, stm, bucket, cnt);
    hipLaunchKernelGGL(k_binsetup, dim3(1), dim3(64), 0, stream, cnt, basep, cursor);
    hipLaunchKernelGGL(k_binscatter, dim3(BATCH / 256), dim3(256), 0, stream, bucket, cursor, order);

    hipFuncSetAttribute(reinterpret_cast<const void*>(k_main),
                        hipFuncAttributeMaxDynamicSharedMemorySize, LDS_BYTES);
    hipLaunchKernelGGL(k_main, dim3(MAXBLK), dim3(NT), LDS_BYTES, stream,
                       stm, nstm, Wacc, bacc, b1, W2, b2, W3, b3,
                       wacc16, w116, cnt, basep, order, out);
}

// Round 2
// 368.580 us; speedup vs baseline: 2.1473x; 2.1473x over previous
//
#include <hip/hip_runtime.h>

typedef _Float16 f16;
typedef f16 f16x8 __attribute__((ext_vector_type(8)));
typedef float f32x4 __attribute__((ext_vector_type(4)));

#define BATCH   32768
#define NF      162
#define ACCH    1024      // hidden accumulator width (without psqt)
#define KSL     192       // K padded to 192 halfs (6 x K=32 MFMA steps)
#define KSLOTS  24        // 16B slots per row (192/8)
#define NB      8
#define DIVQ    20
#define TM      64        // rows per block
#define NT      512       // threads per block
#define NCH     128       // hidden chunk
#define MAXBLK  (BATCH/TM + NB - 1)   // 519

// binning partition
#define BINBLK  256                   // blocks in binning kernels
#define RPB     (BATCH / BINBLK)      // 128 rows per binning block

// workspace layout (bytes)
#define WS_WACC16   0
#define WS_W116     (WS_WACC16 + ACCH*KSL*2)       // 393216
#define WS_BUCKET   (WS_W116 + 256*2048*2)         // 1441792
#define WS_ORDER    (WS_BUCKET + BATCH*4)          // 1572864
#define WS_CNT      (WS_ORDER + BATCH*4)           // 1703936
#define WS_BASE     (WS_CNT + 64)
#define WS_PART     (WS_BASE + 64)                 // BINBLK*8 ints = 8192 B
#define WS_BB       (WS_PART + BINBLK*8*4)         // BINBLK*8 ints = 8192 B

#define LDS_BYTES   115840

// ---------------- prep: convert weights to f16 (padded) ----------------
__global__ void k_prep(const float* __restrict__ Wacc, const float* __restrict__ W1,
                       f16* __restrict__ wacc16, f16* __restrict__ w116)
{
    int tid = blockIdx.x * blockDim.x + threadIdx.x;
    int stride = gridDim.x * blockDim.x;
    for (int t = tid; t < ACCH * KSL; t += stride) {
        int r = t / KSL, k = t - r * KSL;
        float v = (k < NF) ? Wacc[r * NF + k] : 0.f;
        wacc16[t] = (f16)v;
    }
    for (int t = tid; t < 256 * 2048; t += stride) {
        w116[t] = (f16)W1[t];
    }
}

// ---------------- binning: bucket per row + per-block histogram (no global atomics) ----------------
__global__ __launch_bounds__(256) void k_bincount(const float* __restrict__ stm,
                                                  int* __restrict__ bucket,
                                                  int* __restrict__ part)
{
    __shared__ int hist[NB];
    int tid = threadIdx.x;
    if (tid < NB) hist[tid] = 0;
    __syncthreads();
    int wv = tid >> 6, ln = tid & 63;
    int blkstart = blockIdx.x * RPB;
    // 4 waves, each handles RPB/4 = 32 consecutive rows
    for (int i = 0; i < RPB / 4; i++) {
        int row = blkstart + wv * (RPB / 4) + i;
        const float* rp = stm + (long)row * NF;
        float s = 0.f;
        for (int k = ln; k < NF; k += 64) s += rp[k];
        for (int off = 32; off > 0; off >>= 1) s += __shfl_down(s, off);
        if (ln == 0) {
            int pc = (int)(s + 0.5f);
            int b = pc / DIVQ; if (b > NB - 1) b = NB - 1;
            bucket[row] = b;
            atomicAdd(&hist[b], 1);   // LDS atomic only
        }
    }
    __syncthreads();
    if (tid < NB) part[blockIdx.x * NB + tid] = hist[tid];
}

// single small block: per-bucket totals, bucket bases, per-(block,bucket) bases
__global__ void k_binsetup(const int* __restrict__ part, int* __restrict__ cnt,
                           int* __restrict__ base, int* __restrict__ bb)
{
    __shared__ int tot[NB];
    int tid = threadIdx.x;
    if (tid < NB) {
        int acc = 0;
        for (int blk = 0; blk < BINBLK; blk++) {
            bb[blk * NB + tid] = acc;          // within-bucket exclusive prefix
            acc += part[blk * NB + tid];
        }
        tot[tid] = acc;
        cnt[tid] = acc;
    }
    __syncthreads();
    __shared__ int bas[NB];
    if (tid == 0) {
        int acc = 0;
        for (int b = 0; b < NB; b++) { bas[b] = acc; base[b] = acc; acc += tot[b]; }
    }
    __syncthreads();
    if (tid < NB) {
        int add = bas[tid];
        for (int blk = 0; blk < BINBLK; blk++) bb[blk * NB + tid] += add;
    }
}

// scatter using precomputed per-block bases; LDS cursors only
__global__ __launch_bounds__(256) void k_binscatter(const int* __restrict__ bucket,
                                                    const int* __restrict__ bb,
                                                    int* __restrict__ order)
{
    __shared__ int lcur[NB];
    int tid = threadIdx.x;
    if (tid < NB) lcur[tid] = bb[blockIdx.x * NB + tid];
    __syncthreads();
    int blkstart = blockIdx.x * RPB;
    for (int i = tid; i < RPB; i += 256) {
        int row = blkstart + i;
        int b = bucket[row];
        int pos = atomicAdd(&lcur[b], 1);     // LDS atomic only
        order[pos] = row;
    }
}

// ---------------- fused main kernel ----------------
__global__ __launch_bounds__(NT) void k_main(
    const float* __restrict__ stm, const float* __restrict__ nstm,
    const float* __restrict__ Wacc, const float* __restrict__ bacc,
    const float* __restrict__ b1, const float* __restrict__ W2,
    const float* __restrict__ b2, const float* __restrict__ W3,
    const float* __restrict__ b3,
    const f16* __restrict__ wacc16, const f16* __restrict__ w116,
    const int* __restrict__ cnt, const int* __restrict__ base,
    const int* __restrict__ order,
    float* __restrict__ out)
{
    // ---- block -> (bucket, tile) map (uniform per block) ----
    int bkt = -1, tile = 0, tacc = 0;
    for (int b = 0; b < NB; b++) {
        int tb = (cnt[b] + TM - 1) / TM;
        if (bkt < 0 && (int)blockIdx.x < tacc + tb) { bkt = b; tile = blockIdx.x - tacc; }
        tacc += tb;
    }
    if (bkt < 0) return;
    int rowbase = base[bkt] + tile * TM;
    int nrows = cnt[bkt] - tile * TM; if (nrows > TM) nrows = TM;

    extern __shared__ __align__(16) char lds_raw[];
    f16* Fs   = (f16*)lds_raw;            // [TM][KSL]   swizzled slots
    f16* Wc   = Fs  + TM * KSL;           // [NCH][KSL]  swizzled
    f16* Xb   = Wc  + NCH * KSL;          // [TM][NCH]   swizzled
    f16* W1c  = Xb  + TM * NCH;           // [32][NCH]   swizzled
    f16* h1s  = W1c + 32 * NCH;           // [TM][40]
    f16* h2s  = h1s + TM * 40;            // [TM][40]
    f16* W2c  = h2s + TM * 40;            // [32][40]
    float* baccs = (float*)(W2c + 32 * 40);  // [1024]
    float* psq   = baccs + ACCH;             // [TM]
    float* w3s   = psq + TM;                 // [32]
    int*   idxl  = (int*)(w3s + 32);         // [TM]

    int tid = threadIdx.x;
    int wv = tid >> 6, ln = tid & 63;
    int l15 = ln & 15, l4 = ln >> 4;

    if (tid < TM) {
        int rr = rowbase + tid;
        idxl[tid] = order[(tid < nrows) ? rr : rowbase];
        psq[tid] = 0.f;
    }
    for (int i = tid; i < ACCH; i += NT) baccs[i] = bacc[i];
    if (tid < 32) w3s[tid] = W3[bkt * 32 + tid];
    for (int t = tid; t < 32 * 32; t += NT) {
        int n = t >> 5, k = t & 31;
        W2c[n * 40 + k] = (f16)W2[(bkt * 32 + n) * 32 + k];
    }
    __syncthreads();

    // wave tile assignment
    int mq = wv >> 2;   // phase1: rows mq*32 + {0,16}
    int nq = wv & 3;    // phase1: cols nq*32 + {0,16}
    int mt = wv >> 1;   // phase2/3: M-tile 0..3
    int nh = wv & 1;    // phase2/3: N-half 0..1

    f32x4 h1acc; h1acc[0] = h1acc[1] = h1acc[2] = h1acc[3] = 0.f;

    const float* psqw = Wacc + (long)ACCH * NF;   // psqt weight row (fp32)

    for (int s = 0; s < 2; s++) {
        __syncthreads();  // Fs free
        const float* src = s ? nstm : stm;
        // ---- load feature tile (f16, zero-padded, slot-swizzled) ----
        for (int rr = 0; rr < TM / 8; rr++) {
            int r = wv * 8 + rr;
            const float* rp = src + (long)idxl[r] * NF;
            int x = r & 7;
            for (int k = ln; k < KSL; k += 64) {
                float v = (k < NF) ? rp[k] : 0.f;
                Fs[r * KSL + ((((k >> 3) ^ x) << 3) | (k & 7))] = (f16)v;
            }
        }
        __syncthreads();
        // ---- psqt partial (fp32 exact weights, f16 features are exact 0/1) ----
        if (tid < TM) {
            int r = tid, x = r & 7;
            float a = 0.f;
            for (int k = 0; k < NF; k++) {
                float fv = (float)Fs[r * KSL + ((((k >> 3) ^ x) << 3) | (k & 7))];
                a += fv * psqw[k];
            }
            psq[r] += s ? (-0.5f * a) : (0.5f * a);
        }

        for (int c = 0; c < ACCH / NCH; c++) {
            __syncthreads();  // Wc / W1c / Xb free (prev phase1+2 done)
            // ---- stage W_acc chunk ----
            for (int t = tid; t < NCH * KSLOTS; t += NT) {
                int n = t / KSLOTS, slot = t - n * KSLOTS;
                f16x8 v = *(const f16x8*)(wacc16 + (long)(c * NCH + n) * KSL + slot * 8);
                *(f16x8*)(Wc + n * KSL + ((slot ^ (n & 7)) << 3)) = v;
            }
            // ---- stage W1 chunk for (bucket, s, c) ----
            for (int t = tid; t < 32 * (NCH / 8); t += NT) {
                int n = t >> 4, slot = t & 15;
                f16x8 v = *(const f16x8*)(w116 + (long)(bkt * 32 + n) * 2048 + s * ACCH + c * NCH + slot * 8);
                *(f16x8*)(W1c + n * NCH + ((slot ^ (n & 7)) << 3)) = v;
            }
            __syncthreads();  // Wc, W1c ready

            // ---- phase 1: raw chunk = F @ Wacc_chunk^T, act -> Xb ----
            f32x4 accv[2][2];
            #pragma unroll
            for (int i = 0; i < 2; i++)
                #pragma unroll
                for (int j = 0; j < 2; j++)
                    accv[i][j][0] = accv[i][j][1] = accv[i][j][2] = accv[i][j][3] = 0.f;

            #pragma unroll
            for (int ks = 0; ks < KSL / 32; ks++) {
                int s0 = ks * 4 + l4;
                f16x8 af[2], bf[2];
                #pragma unroll
                for (int i = 0; i < 2; i++) {
                    int row = mq * 32 + i * 16 + l15;
                    af[i] = *(const f16x8*)(Fs + row * KSL + ((s0 ^ (row & 7)) << 3));
                    int nn = nq * 32 + i * 16 + l15;
                    bf[i] = *(const f16x8*)(Wc + nn * KSL + ((s0 ^ (nn & 7)) << 3));
                }
                #pragma unroll
                for (int i = 0; i < 2; i++)
                    #pragma unroll
                    for (int j = 0; j < 2; j++)
                        accv[i][j] = __builtin_amdgcn_mfma_f32_16x16x32_f16(af[i], bf[j], accv[i][j], 0, 0, 0);
            }
            // epilogue: bias + clip^2 -> Xb (f16, swizzled)
            #pragma unroll
            for (int i = 0; i < 2; i++)
                #pragma unroll
                for (int j = 0; j < 2; j++)
                    #pragma unroll
                    for (int jr = 0; jr < 4; jr++) {
                        int row = mq * 32 + i * 16 + l4 * 4 + jr;
                        int col = nq * 32 + j * 16 + l15;
                        float v = accv[i][j][jr] + baccs[c * NCH + col];
                        v = fminf(fmaxf(v, 0.f), 1.f);
                        v = v * v;
                        Xb[row * NCH + ((((col >> 3) ^ (row & 7)) << 3) | (col & 7))] = (f16)v;
                    }
            __syncthreads();  // Xb ready

            // ---- phase 2: h1 += act_chunk @ W1_chunk^T ----
            #pragma unroll
            for (int ks = 0; ks < NCH / 32; ks++) {
                int s0 = ks * 4 + l4;
                int row = mt * 16 + l15;
                f16x8 a = *(const f16x8*)(Xb + row * NCH + ((s0 ^ (row & 7)) << 3));
                int nn = nh * 16 + l15;
                f16x8 b = *(const f16x8*)(W1c + nn * NCH + ((s0 ^ (nn & 7)) << 3));
                h1acc = __builtin_amdgcn_mfma_f32_16x16x32_f16(a, b, h1acc, 0, 0, 0);
            }
        }
    }

    // ---- h1 finalize: bias + clip [0,1] ----
    #pragma unroll
    for (int jr = 0; jr < 4; jr++) {
        int row = mt * 16 + l4 * 4 + jr;
        int col = nh * 16 + l15;
        float v = h1acc[jr] + b1[bkt * 32 + col];
        v = fminf(fmaxf(v, 0.f), 1.f);
        h1s[row * 40 + col] = (f16)v;
    }
    __syncthreads();

    // ---- layer 3: h2 = clip(h1 @ W2_b^T + b2, 0, 1) ----
    {
        int row = mt * 16 + l15;
        f16x8 a = *(const f16x8*)(h1s + row * 40 + l4 * 8);
        int nn = nh * 16 + l15;
        f16x8 b = *(const f16x8*)(W2c + nn * 40 + l4 * 8);
        f32x4 acc; acc[0] = acc[1] = acc[2] = acc[3] = 0.f;
        acc = __builtin_amdgcn_mfma_f32_16x16x32_f16(a, b, acc, 0, 0, 0);
        #pragma unroll
        for (int jr = 0; jr < 4; jr++) {
            int r2 = mt * 16 + l4 * 4 + jr;
            int c2 = nh * 16 + l15;
            float v = acc[jr] + b2[bkt * 32 + c2];
            v = fminf(fmaxf(v, 0.f), 1.f);
            h2s[r2 * 40 + c2] = (f16)v;
        }
    }
    __syncthreads();

    // ---- layer 4 + psqt -> output ----
    if (tid < nrows) {
        float o = b3[bkt] + psq[tid];
        #pragma unroll 8
        for (int n = 0; n < 32; n++) o += (float)h2s[tid * 40 + n] * w3s[n];
        out[idxl[tid]] = o;
    }
}

// ---------------- launcher ----------------
extern "C" void kernel_launch(void* const* d_in, const int* in_sizes, int n_in,
                              void* d_out, int out_size, void* d_ws, size_t ws_size,
                              hipStream_t stream)
{
    (void)in_sizes; (void)n_in; (void)out_size; (void)ws_size;
    const float* stm  = (const float*)d_in[0];
    const float* nstm = (const float*)d_in[1];
    const float* Wacc = (const float*)d_in[2];
    const float* bacc = (const float*)d_in[3];
    const float* W1   = (const float*)d_in[4];
    const float* b1   = (const float*)d_in[5];
    const float* W2   = (const float*)d_in[6];
    const float* b2   = (const float*)d_in[7];
    const float* W3   = (const float*)d_in[8];
    const float* b3   = (const float*)d_in[9];
    float* out = (float*)d_out;

    char* ws = (char*)d_ws;
    f16* wacc16 = (f16*)(ws + WS_WACC16);
    f16* w116   = (f16*)(ws + WS_W116);
    int* bucket = (int*)(ws + WS_BUCKET);
    int* order  = (int*)(ws + WS_ORDER);
    int* cnt    = (int*)(ws + WS_CNT);
    int* basep  = (int*)(ws + WS_BASE);
    int* part   = (int*)(ws + WS_PART);
    int* bb     = (int*)(ws + WS_BB);

    hipLaunchKernelGGL(k_prep, dim3(1024), dim3(256), 0, stream, Wacc, W1, wacc16, w116);
    hipLaunchKernelGGL(k_bincount, dim3(BINBLK), dim3(256), 0, stream, stm, bucket, part);
    hipLaunchKernelGGL(k_binsetup, dim3(1), dim3(64), 0, stream, part, cnt, basep, bb);
    hipLaunchKernelGGL(k_binscatter, dim3(BINBLK), dim3(256), 0, stream, bucket, bb, order);

    hipFuncSetAttribute(reinterpret_cast<const void*>(k_main),
                        hipFuncAttributeMaxDynamicSharedMemorySize, LDS_BYTES);
    hipLaunchKernelGGL(k_main, dim3(MAXBLK), dim3(NT), LDS_BYTES, stream,
                       stm, nstm, Wacc, bacc, b1, W2, b2, W3, b3,
                       wacc16, w116, cnt, basep, order, out);
}

// Round 3
// 283.732 us; speedup vs baseline: 2.7895x; 1.2990x over previous
//
#include <hip/hip_runtime.h>

typedef _Float16 f16;
typedef f16 f16x8 __attribute__((ext_vector_type(8)));
typedef float f32x4 __attribute__((ext_vector_type(4)));

#define BATCH   32768
#define NF      162
#define ACCH    1024      // hidden accumulator width (without psqt)
#define KSL     192       // K padded to 192 halfs (6 x K=32 MFMA steps)
#define NKS     (KSL/32)  // 6
#define NB      8
#define DIVQ    20
#define TM      64        // rows per block
#define NT      512       // threads per block
#define NCH     128       // hidden chunk
#define NCHUNK  (ACCH/NCH) // 8
#define MAXBLK  (BATCH/TM + NB - 1)   // 519

// binning partition
#define BINBLK  256
#define RPB     (BATCH / BINBLK)      // 128 rows per binning block

// workspace layout (bytes)
#define WS_WACC16   0
#define WS_W116     (WS_WACC16 + ACCH*KSL*2)       // 393216
#define WS_BUCKET   (WS_W116 + 256*2048*2)         // 1441792
#define WS_ORDER    (WS_BUCKET + BATCH*4)          // 1572864
#define WS_CNT      (WS_ORDER + BATCH*4)           // 1703936
#define WS_BASE     (WS_CNT + 64)
#define WS_PART     (WS_BASE + 64)                 // BINBLK*8 ints = 8192 B
#define WS_BB       (WS_PART + BINBLK*8*4)         // BINBLK*8 ints = 8192 B
#define WS_BLKMAP   WS_PART                        // reuse: part dead after binsetup reads it

// LDS: Fs 24576 + Xb(2) 32768 + h1s 5120 + h2s 5120 + W2c 2560 + psq 256 + w3s 128 + idxl 256
#define LDS_BYTES   70784

// ---------------- prep: weights -> f16 fragment-major layouts ----------------
// waccF frag index: ((c*NKS+ks)*4 + l4)*128 + n  (f16x8 units); element k = ks*32+l4*8+e
// w1F   frag index: (((bkt*2+s)*8+c)*16 + ks*4 + l4)*32 + n ; k = s*1024+c*128+ks*32+l4*8+e
__global__ void k_prep(const float* __restrict__ Wacc, const float* __restrict__ W1,
                       f16* __restrict__ waccF, f16* __restrict__ w1F)
{
    int tid = blockIdx.x * blockDim.x + threadIdx.x;
    int stride = gridDim.x * blockDim.x;
    for (int t = tid; t < ACCH * KSL; t += stride) {
        int e = t & 7, f = t >> 3;
        int n = f & 127, g = f >> 7;
        int l4 = g & 3, h = g >> 2;
        int ks = h % NKS, c = h / NKS;
        int k = ks * 32 + l4 * 8 + e;
        int row = c * 128 + n;
        waccF[t] = (f16)((k < NF) ? Wacc[row * NF + k] : 0.f);
    }
    for (int t = tid; t < 256 * 2048; t += stride) {
        int e = t & 7, f = t >> 3;
        int n = f & 31, g = f >> 5;
        int l4 = g & 3, h = g >> 2;
        int ks = h & 3, g2 = h >> 2;
        int c = g2 & 7, m = g2 >> 3;
        int s = m & 1, bkt = m >> 1;
        int k = s * ACCH + c * NCH + ks * 32 + l4 * 8 + e;
        w1F[t] = (f16)W1[(bkt * 32 + n) * 2048 + k];
    }
}

// ---------------- binning ----------------
__global__ __launch_bounds__(512) void k_bincount(const float* __restrict__ stm,
                                                  int* __restrict__ bucket,
                                                  int* __restrict__ part)
{
    __shared__ int hist[NB];
    int tid = threadIdx.x;
    if (tid < NB) hist[tid] = 0;
    __syncthreads();
    int wv = tid >> 6, ln = tid & 63;
    int rowbase = blockIdx.x * RPB + wv * (RPB / 8);   // 16 rows per wave
    for (int i = 0; i < RPB / 8; i++) {
        int row = rowbase + i;
        const float* rp = stm + (long)row * NF;
        float s = 0.f;
        for (int k = ln; k < NF; k += 64) s += rp[k];
        for (int off = 32; off > 0; off >>= 1) s += __shfl_down(s, off);
        if (ln == 0) {
            int pc = (int)(s + 0.5f);
            int b = pc / DIVQ; if (b > NB - 1) b = NB - 1;
            bucket[row] = b;
            atomicAdd(&hist[b], 1);
        }
    }
    __syncthreads();
    if (tid < NB) part[blockIdx.x * NB + tid] = hist[tid];
}

__global__ __launch_bounds__(512) void k_binsetup(const int* __restrict__ part,
                                                  int* __restrict__ cnt,
                                                  int* __restrict__ base,
                                                  int* __restrict__ bb,
                                                  int* __restrict__ blkmap)
{
    __shared__ int tot[NB], bas[NB], tstart[NB + 1];
    int tid = threadIdx.x;
    if (tid < NB) {
        int acc = 0;
        for (int blk = 0; blk < BINBLK; blk++) {
            bb[blk * NB + tid] = acc;
            acc += part[blk * NB + tid];
        }
        tot[tid] = acc;
        cnt[tid] = acc;
    }
    __syncthreads();
    if (tid == 0) {
        int a = 0;
        for (int b = 0; b < NB; b++) { bas[b] = a; base[b] = a; a += tot[b]; }
        int t = 0;
        for (int b = 0; b < NB; b++) { tstart[b] = t; t += (tot[b] + TM - 1) / TM; }
        tstart[NB] = t;
    }
    __syncthreads();
    if (tid < NB) {
        int add = bas[tid];
        for (int blk = 0; blk < BINBLK; blk++) bb[blk * NB + tid] += add;
    }
    for (int i = tid; i < MAXBLK; i += blockDim.x) {
        int v = -1;
        for (int b = 0; b < NB; b++)
            if (i >= tstart[b] && i < tstart[b + 1]) v = b | ((i - tstart[b]) << 4);
        blkmap[i] = v;
    }
}

__global__ __launch_bounds__(256) void k_binscatter(const int* __restrict__ bucket,
                                                    const int* __restrict__ bb,
                                                    int* __restrict__ order)
{
    __shared__ int lcur[NB];
    int tid = threadIdx.x;
    if (tid < NB) lcur[tid] = bb[blockIdx.x * NB + tid];
    __syncthreads();
    int blkstart = blockIdx.x * RPB;
    for (int i = tid; i < RPB; i += 256) {
        int row = blkstart + i;
        int b = bucket[row];
        int pos = atomicAdd(&lcur[b], 1);
        order[pos] = row;
    }
}

// ---------------- fused main kernel ----------------
__global__ __launch_bounds__(NT, 4) void k_main(
    const float* __restrict__ stm, const float* __restrict__ nstm,
    const float* __restrict__ Wacc, const float* __restrict__ bacc,
    const float* __restrict__ b1, const float* __restrict__ W2,
    const float* __restrict__ b2, const float* __restrict__ W3,
    const float* __restrict__ b3,
    const f16* __restrict__ waccF, const f16* __restrict__ w1F,
    const int* __restrict__ cnt, const int* __restrict__ base,
    const int* __restrict__ order, const int* __restrict__ blkmap,
    float* __restrict__ out)
{
    int bm = blkmap[blockIdx.x];
    if (bm < 0) return;
    int bkt = bm & 15, tile = bm >> 4;
    int rowbase = base[bkt] + tile * TM;
    int nrows = cnt[bkt] - tile * TM; if (nrows > TM) nrows = TM;

    extern __shared__ __align__(16) char lds_raw[];
    f16* Fs   = (f16*)lds_raw;            // [TM][KSL]  swizzled
    f16* Xb   = Fs  + TM * KSL;           // [2][TM][NCH] swizzled, double-buffered
    f16* h1s  = Xb  + 2 * TM * NCH;       // [TM][40]
    f16* h2s  = h1s + TM * 40;            // [TM][40]
    f16* W2c  = h2s + TM * 40;            // [32][40]
    float* psq  = (float*)(W2c + 32 * 40); // [TM]
    float* w3s  = psq + TM;                // [32]
    int*   idxl = (int*)(w3s + 32);        // [TM]

    int tid = threadIdx.x;
    int wv = tid >> 6, ln = tid & 63;
    int l15 = ln & 15, l4 = ln >> 4;

    if (tid < TM) {
        int rr = rowbase + tid;
        idxl[tid] = order[(tid < nrows) ? rr : rowbase];
    }
    if (tid < 32) w3s[tid] = W3[bkt * 32 + tid];
    for (int t = tid; t < 32 * 32; t += NT) {
        int n = t >> 5, k = t & 31;
        W2c[n * 40 + k] = (f16)W2[(bkt * 32 + n) * 32 + k];
    }
    __syncthreads();

    // wave tile assignment
    int mt = wv >> 1;   // phase2/3: M-tile 0..3
    int nh = wv & 1;    // phase2/3: N-half 0..1

    float bb1 = b1[bkt * 32 + nh * 16 + l15];
    f32x4 h1acc; h1acc[0] = h1acc[1] = h1acc[2] = h1acc[3] = bb1;

    const float* psqw = Wacc + (long)ACCH * NF;   // psqt weight row (fp32)
    const f16x8* wfr  = (const f16x8*)waccF;
    const f16x8* w1fr = (const f16x8*)w1F;

    for (int s = 0; s < 2; s++) {
        const float* src = s ? nstm : stm;
        // ---- load feature tile (f16, zero-padded, slot-swizzled) ----
        for (int rr = 0; rr < TM / 8; rr++) {
            int r = wv * 8 + rr;
            const float* rp = src + (long)idxl[r] * NF;
            int x = r & 7;
            for (int k = ln; k < KSL; k += 64) {
                float v = (k < NF) ? rp[k] : 0.f;
                Fs[r * KSL + ((((k >> 3) ^ x) << 3) | (k & 7))] = (f16)v;
            }
        }
        __syncthreads();  // Fs ready

        // ---- psqt: 8 threads per row, strided partials, shfl reduce ----
        {
            int row = tid >> 3, p = tid & 7;
            int x = row & 7;
            float a = 0.f;
            #pragma unroll 4
            for (int i = 0; i < 24; i++) {
                int k = p * 24 + i;
                if (k < NF) {
                    float fv = (float)Fs[row * KSL + ((((k >> 3) ^ x) << 3) | (k & 7))];
                    a += fv * psqw[k];
                }
            }
            a += __shfl_xor(a, 1);
            a += __shfl_xor(a, 2);
            a += __shfl_xor(a, 4);
            if (p == 0) {
                if (s) psq[row] -= 0.5f * a;
                else   psq[row]  = 0.5f * a;
            }
        }

        for (int c = 0; c < NCHUNK; c++) {
            // ---- phase 1: 64 rows x 16 cols per wave; B-frags direct from global ----
            int col = (wv << 4) + l15;                 // column within chunk
            float bias = bacc[c * NCH + col];
            f32x4 acc[4];
            #pragma unroll
            for (int i = 0; i < 4; i++) { acc[i][0] = acc[i][1] = acc[i][2] = acc[i][3] = bias; }

            #pragma unroll
            for (int ks = 0; ks < NKS; ks++) {
                f16x8 bf = wfr[((c * NKS + ks) * 4 + l4) * 128 + col];
                int s0 = ks * 4 + l4;
                #pragma unroll
                for (int i = 0; i < 4; i++) {
                    int row = i * 16 + l15;
                    f16x8 af = *(const f16x8*)(Fs + row * KSL + ((s0 ^ (row & 7)) << 3));
                    acc[i] = __builtin_amdgcn_mfma_f32_16x16x32_f16(af, bf, acc[i], 0, 0, 0);
                }
            }
            // epilogue: clip^2 -> Xb[c&1] (f16, swizzled)
            f16* xb = Xb + (c & 1) * TM * NCH;
            int csw = ((col >> 3) << 3) | (col & 7);   // slot,elem of col (pre-xor)
            #pragma unroll
            for (int i = 0; i < 4; i++)
                #pragma unroll
                for (int jr = 0; jr < 4; jr++) {
                    int row = i * 16 + l4 * 4 + jr;
                    float v = acc[i][jr];
                    v = fminf(fmaxf(v, 0.f), 1.f);
                    v = v * v;
                    xb[row * NCH + (csw ^ ((row & 7) << 3))] = (f16)v;
                }
            __syncthreads();  // Xb[c&1] ready (and Xb[(c+1)&1] free)

            // ---- phase 2: h1 += act_chunk @ W1_chunk^T, B-frags direct from global ----
            const f16x8* w1p = w1fr + ((bkt * 2 + s) * 8 + c) * 512;
            #pragma unroll
            for (int ks = 0; ks < NCH / 32; ks++) {
                int s0 = ks * 4 + l4;
                int row = mt * 16 + l15;
                f16x8 a = *(const f16x8*)(xb + row * NCH + ((s0 ^ (row & 7)) << 3));
                f16x8 b = w1p[s0 * 32 + nh * 16 + l15];
                h1acc = __builtin_amdgcn_mfma_f32_16x16x32_f16(a, b, h1acc, 0, 0, 0);
            }
        }
        // loop to next side: Fs overwrite is safe (last Fs reads were phase1 of c=7,
        // which completed before the barrier inside chunk 7)
    }

    // ---- h1 finalize: clip [0,1] (bias was in C-init) ----
    #pragma unroll
    for (int jr = 0; jr < 4; jr++) {
        int row = mt * 16 + l4 * 4 + jr;
        int col = nh * 16 + l15;
        float v = fminf(fmaxf(h1acc[jr], 0.f), 1.f);
        h1s[row * 40 + col] = (f16)v;
    }
    __syncthreads();

    // ---- layer 3: h2 = clip(h1 @ W2_b^T + b2, 0, 1) ----
    {
        float bb2 = b2[bkt * 32 + nh * 16 + l15];
        int row = mt * 16 + l15;
        f16x8 a = *(const f16x8*)(h1s + row * 40 + l4 * 8);
        int nn = nh * 16 + l15;
        f16x8 b = *(const f16x8*)(W2c + nn * 40 + l4 * 8);
        f32x4 acc; acc[0] = acc[1] = acc[2] = acc[3] = bb2;
        acc = __builtin_amdgcn_mfma_f32_16x16x32_f16(a, b, acc, 0, 0, 0);
        #pragma unroll
        for (int jr = 0; jr < 4; jr++) {
            int r2 = mt * 16 + l4 * 4 + jr;
            int c2 = nh * 16 + l15;
            float v = fminf(fmaxf(acc[jr], 0.f), 1.f);
            h2s[r2 * 40 + c2] = (f16)v;
        }
    }
    __syncthreads();

    // ---- layer 4 + psqt -> output ----
    if (tid < nrows) {
        float o = b3[bkt] + psq[tid];
        #pragma unroll 8
        for (int n = 0; n < 32; n++) o += (float)h2s[tid * 40 + n] * w3s[n];
        out[idxl[tid]] = o;
    }
}

// ---------------- launcher ----------------
extern "C" void kernel_launch(void* const* d_in, const int* in_sizes, int n_in,
                              void* d_out, int out_size, void* d_ws, size_t ws_size,
                              hipStream_t stream)
{
    (void)in_sizes; (void)n_in; (void)out_size; (void)ws_size;
    const float* stm  = (const float*)d_in[0];
    const float* nstm = (const float*)d_in[1];
    const float* Wacc = (const float*)d_in[2];
    const float* bacc = (const float*)d_in[3];
    const float* W1   = (const float*)d_in[4];
    const float* b1   = (const float*)d_in[5];
    const float* W2   = (const float*)d_in[6];
    const float* b2   = (const float*)d_in[7];
    const float* W3   = (const float*)d_in[8];
    const float* b3   = (const float*)d_in[9];
    float* out = (float*)d_out;

    char* ws = (char*)d_ws;
    f16* waccF  = (f16*)(ws + WS_WACC16);
    f16* w1F    = (f16*)(ws + WS_W116);
    int* bucket = (int*)(ws + WS_BUCKET);
    int* order  = (int*)(ws + WS_ORDER);
    int* cnt    = (int*)(ws + WS_CNT);
    int* basep  = (int*)(ws + WS_BASE);
    int* part   = (int*)(ws + WS_PART);
    int* bb     = (int*)(ws + WS_BB);
    int* blkmap = (int*)(ws + WS_BLKMAP);   // aliases part (dead after binsetup)

    hipLaunchKernelGGL(k_prep, dim3(1024), dim3(256), 0, stream, Wacc, W1, waccF, w1F);
    hipLaunchKernelGGL(k_bincount, dim3(BINBLK), dim3(512), 0, stream, stm, bucket, part);
    hipLaunchKernelGGL(k_binsetup, dim3(1), dim3(512), 0, stream, part, cnt, basep, bb, blkmap);
    hipLaunchKernelGGL(k_binscatter, dim3(BINBLK), dim3(256), 0, stream, bucket, bb, order);

    hipFuncSetAttribute(reinterpret_cast<const void*>(k_main),
                        hipFuncAttributeMaxDynamicSharedMemorySize, LDS_BYTES);
    hipLaunchKernelGGL(k_main, dim3(MAXBLK), dim3(NT), LDS_BYTES, stream,
                       stm, nstm, Wacc, bacc, b1, W2, b2, W3, b3,
                       waccF, w1F, cnt, basep, order, blkmap, out);
}

// Round 4
// 266.750 us; speedup vs baseline: 2.9671x; 1.0637x over previous
//
#include <hip/hip_runtime.h>

typedef _Float16 f16;
typedef f16 f16x8 __attribute__((ext_vector_type(8)));
typedef float f32x4 __attribute__((ext_vector_type(4)));
typedef float f32x16 __attribute__((ext_vector_type(16)));

#define BATCH   32768
#define NF      162
#define ACCH    1024      // hidden accumulator width (without psqt)
#define KSL     192       // K padded to 192 halfs
#define NKS2    12        // 32x32x16 K-steps per 192
#define NB      8
#define DIVQ    20
#define TM      64        // rows per block
#define NT      512       // threads per block
#define NCH     128       // hidden chunk
#define NCHUNK  (ACCH/NCH) // 8
#define MAXBLK  (BATCH/TM + NB - 1)   // 519

// binning partition
#define BINBLK  256
#define RPB     (BATCH / BINBLK)      // 128 rows per binning block

// workspace layout (bytes)
#define WS_WACC16   0
#define WS_W116     (WS_WACC16 + ACCH*KSL*2)       // 393216
#define WS_BUCKET   (WS_W116 + 256*2048*2)         // 1441792
#define WS_ORDER    (WS_BUCKET + BATCH*4)          // 1572864
#define WS_CNT      (WS_ORDER + BATCH*4)           // 1703936
#define WS_BASE     (WS_CNT + 64)
#define WS_PART     (WS_BASE + 64)                 // BINBLK*8 ints
#define WS_BB       (WS_PART + BINBLK*8*4)         // BINBLK*8 ints
#define WS_BLKMAP   WS_PART                        // reuse: part dead after binsetup reads it

// LDS: Fs 24576 (h1s/h2s alias) + Xb 16384 + psq 256 + idxl 256
#define LDS_BYTES   41472

// ---------------- prep: weights -> f16 fragment-major layouts ----------------
// waccF (32x32x16 B-frag): u16 idx = (((c*12+ks)*2 + kh)*128 + n)*8 + e
//   value = Wacc[c*128+n][k], k = ks*16 + kh*8 + e (0 if k>=NF)
// w1F (16x16x32 B-frag): u16 idx = ((((bkt*2+s)*8+c)*16 + ks*4 + l4)*32 + n)*8 + e
//   value = W1[bkt*32+n][s*1024 + c*128 + ks*32 + l4*8 + e]
__global__ void k_prep(const float* __restrict__ Wacc, const float* __restrict__ W1,
                       f16* __restrict__ waccF, f16* __restrict__ w1F)
{
    int tid = blockIdx.x * blockDim.x + threadIdx.x;
    int stride = gridDim.x * blockDim.x;
    for (int t = tid; t < ACCH * KSL; t += stride) {
        int e = t & 7, f = t >> 3;
        int n = f & 127, g = f >> 7;
        int kh = g & 1, h = g >> 1;
        int ks = h % NKS2, c = h / NKS2;
        int k = ks * 16 + kh * 8 + e;
        int row = c * 128 + n;
        waccF[t] = (f16)((k < NF) ? Wacc[row * NF + k] : 0.f);
    }
    for (int t = tid; t < 256 * 2048; t += stride) {
        int e = t & 7, f = t >> 3;
        int n = f & 31, g = f >> 5;
        int l4 = g & 3, h = g >> 2;
        int ks = h & 3, g2 = h >> 2;
        int c = g2 & 7, m = g2 >> 3;
        int s = m & 1, bkt = m >> 1;
        int k = s * ACCH + c * NCH + ks * 32 + l4 * 8 + e;
        w1F[t] = (f16)W1[(bkt * 32 + n) * 2048 + k];
    }
}

// ---------------- binning ----------------
__global__ __launch_bounds__(512) void k_bincount(const float* __restrict__ stm,
                                                  int* __restrict__ bucket,
                                                  int* __restrict__ part)
{
    __shared__ int hist[NB];
    int tid = threadIdx.x;
    if (tid < NB) hist[tid] = 0;
    __syncthreads();
    int wv = tid >> 6, ln = tid & 63;
    int rowbase = blockIdx.x * RPB + wv * (RPB / 8);   // 16 rows per wave
    for (int i = 0; i < RPB / 8; i++) {
        int row = rowbase + i;
        const float* rp = stm + (long)row * NF;
        float s = 0.f;
        for (int k = ln; k < NF; k += 64) s += rp[k];
        for (int off = 32; off > 0; off >>= 1) s += __shfl_down(s, off);
        if (ln == 0) {
            int pc = (int)(s + 0.5f);
            int b = pc / DIVQ; if (b > NB - 1) b = NB - 1;
            bucket[row] = b;
            atomicAdd(&hist[b], 1);
        }
    }
    __syncthreads();
    if (tid < NB) part[blockIdx.x * NB + tid] = hist[tid];
}

// 8 waves, one per bucket: parallel prefix over 256 per-block partials
__global__ __launch_bounds__(512) void k_binsetup(const int* __restrict__ part,
                                                  int* __restrict__ cnt,
                                                  int* __restrict__ base,
                                                  int* __restrict__ bb,
                                                  int* __restrict__ blkmap)
{
    __shared__ int tot[NB], bas[NB], tstart[NB + 1];
    int tid = threadIdx.x;
    int wv = tid >> 6, ln = tid & 63;
    int b = wv;
    int v0 = part[(ln * 4 + 0) * NB + b];
    int v1 = part[(ln * 4 + 1) * NB + b];
    int v2 = part[(ln * 4 + 2) * NB + b];
    int v3 = part[(ln * 4 + 3) * NB + b];
    int s = v0 + v1 + v2 + v3;
    int inc = s;
    for (int off = 1; off < 64; off <<= 1) {
        int n = __shfl_up(inc, off);
        if (ln >= off) inc += n;
    }
    int exc = inc - s;
    if (ln == 63) tot[b] = inc;
    __syncthreads();
    if (tid == 0) {
        int a = 0;
        for (int q = 0; q < NB; q++) { bas[q] = a; base[q] = a; a += tot[q]; }
        int t = 0;
        for (int q = 0; q < NB; q++) { tstart[q] = t; t += (tot[q] + TM - 1) / TM; }
        tstart[NB] = t;
        for (int q = 0; q < NB; q++) cnt[q] = tot[q];
    }
    __syncthreads();
    int run = exc + bas[b];
    bb[(ln * 4 + 0) * NB + b] = run; run += v0;
    bb[(ln * 4 + 1) * NB + b] = run; run += v1;
    bb[(ln * 4 + 2) * NB + b] = run; run += v2;
    bb[(ln * 4 + 3) * NB + b] = run;
    for (int i = tid; i < MAXBLK; i += 512) {
        int v = -1;
        for (int q = 0; q < NB; q++)
            if (i >= tstart[q] && i < tstart[q + 1]) v = q | ((i - tstart[q]) << 4);
        blkmap[i] = v;
    }
}

__global__ __launch_bounds__(256) void k_binscatter(const int* __restrict__ bucket,
                                                    const int* __restrict__ bb,
                                                    int* __restrict__ order)
{
    __shared__ int lcur[NB];
    int tid = threadIdx.x;
    if (tid < NB) lcur[tid] = bb[blockIdx.x * NB + tid];
    __syncthreads();
    int blkstart = blockIdx.x * RPB;
    for (int i = tid; i < RPB; i += 256) {
        int row = blkstart + i;
        int b = bucket[row];
        int pos = atomicAdd(&lcur[b], 1);
        order[pos] = row;
    }
}

// ---------------- fused main kernel ----------------
__global__ __launch_bounds__(NT, 6) void k_main(
    const float* __restrict__ stm, const float* __restrict__ nstm,
    const float* __restrict__ Wacc, const float* __restrict__ bacc,
    const float* __restrict__ b1, const float* __restrict__ W2,
    const float* __restrict__ b2, const float* __restrict__ W3,
    const float* __restrict__ b3,
    const f16* __restrict__ waccF, const f16* __restrict__ w1F,
    const int* __restrict__ cnt, const int* __restrict__ base,
    const int* __restrict__ order, const int* __restrict__ blkmap,
    float* __restrict__ out)
{
    int bm = blkmap[blockIdx.x];
    if (bm < 0) return;
    int bkt = bm & 15, tile = bm >> 4;
    int rowbase = base[bkt] + tile * TM;
    int nrows = cnt[bkt] - tile * TM; if (nrows > TM) nrows = TM;

    extern __shared__ __align__(16) char lds_raw[];
    f16* Fs   = (f16*)lds_raw;                         // [64][192] swizzled
    f16* Xb   = (f16*)(lds_raw + TM * KSL * 2);        // [64][128] swizzled (single buffer)
    float* psq  = (float*)(lds_raw + TM * KSL * 2 + TM * NCH * 2);   // [64]
    int*   idxl = (int*)((char*)psq + TM * 4);                       // [64]
    f16* h1s  = (f16*)lds_raw;                         // [64][40], aliases Fs (dead)
    f16* h2s  = (f16*)(lds_raw + TM * 40 * 2);         // [64][40], aliases Fs

    int tid = threadIdx.x;
    int wv = tid >> 6, ln = tid & 63;
    int l15 = ln & 15, l4 = ln >> 4;
    int col31 = ln & 31, kh = ln >> 5;

    if (tid < TM) {
        int rr = rowbase + tid;
        idxl[tid] = order[(tid < nrows) ? rr : rowbase];
    }
    __syncthreads();

    // wave tile assignment
    int wr = wv & 1;    // phase1 row-half
    int wc = wv >> 1;   // phase1 col-quarter
    int mt = wv >> 1;   // phase2/3: M-tile 0..3
    int nh = wv & 1;    // phase2/3: N-half 0..1

    int arow = wr * 32 + col31;
    int axor = arow & 7;
    int colc = wc * 32 + col31;   // col within chunk (0..127)

    float bb1 = b1[bkt * 32 + nh * 16 + l15];
    f32x4 h1acc; h1acc[0] = h1acc[1] = h1acc[2] = h1acc[3] = bb1;

    const float* psqw = Wacc + (long)ACCH * NF;   // psqt weight row (fp32)
    const f16x8* wfr  = (const f16x8*)waccF;
    const f16x8* w1fr = (const f16x8*)w1F;

    int rloc = ln >> 3, j = ln & 7;
    int srow = wv * 8 + rloc;            // staging row owned by this lane
    int sxor = srow & 7;

    for (int s = 0; s < 2; s++) {
        const float* src = s ? nstm : stm;
        // ---- fused feature staging + psqt (vectorized, ds_write_b128) ----
        {
            const float* rp = src + (long)idxl[srow] * NF;
            float pp = 0.f;
            #pragma unroll
            for (int bq = 0; bq < 3; bq++) {
                int slot = j + bq * 8;
                int k0 = slot * 8;
                float f0=0.f,f1=0.f,f2=0.f,f3=0.f,f4=0.f,f5=0.f,f6=0.f,f7=0.f;
                if (slot < 20) {
                    float2 a0 = *(const float2*)(rp + k0);
                    float2 a1 = *(const float2*)(rp + k0 + 2);
                    float2 a2 = *(const float2*)(rp + k0 + 4);
                    float2 a3 = *(const float2*)(rp + k0 + 6);
                    f0=a0.x; f1=a0.y; f2=a1.x; f3=a1.y;
                    f4=a2.x; f5=a2.y; f6=a3.x; f7=a3.y;
                    pp += f0*psqw[k0]   + f1*psqw[k0+1] + f2*psqw[k0+2] + f3*psqw[k0+3]
                        + f4*psqw[k0+4] + f5*psqw[k0+5] + f6*psqw[k0+6] + f7*psqw[k0+7];
                } else if (slot == 20) {
                    float2 a0 = *(const float2*)(rp + 160);
                    f0 = a0.x; f1 = a0.y;
                    pp += f0*psqw[160] + f1*psqw[161];
                }
                f16x8 h;
                h[0]=(f16)f0; h[1]=(f16)f1; h[2]=(f16)f2; h[3]=(f16)f3;
                h[4]=(f16)f4; h[5]=(f16)f5; h[6]=(f16)f6; h[7]=(f16)f7;
                *(f16x8*)(Fs + srow * KSL + ((slot ^ sxor) << 3)) = h;
            }
            pp += __shfl_xor(pp, 1);
            pp += __shfl_xor(pp, 2);
            pp += __shfl_xor(pp, 4);
            if (j == 0) {
                if (s) psq[srow] -= 0.5f * pp;
                else   psq[srow]  = 0.5f * pp;
            }
        }
        __syncthreads();  // Fs ready

        for (int c = 0; c < NCHUNK; c++) {
            // ---- phase 1: 32x32 MFMA, wave = rows [wr*32,+32) x cols [wc*32,+32) ----
            float bias = bacc[c * NCH + colc];
            f32x16 acc;
            #pragma unroll
            for (int q = 0; q < 16; q++) acc[q] = bias;

            #pragma unroll
            for (int ks = 0; ks < NKS2; ks++) {
                f16x8 bf = wfr[((c * NKS2 + ks) * 2 + kh) * 128 + colc];
                int slot = ks * 2 + kh;
                f16x8 af = *(const f16x8*)(Fs + arow * KSL + ((slot ^ axor) << 3));
                acc = __builtin_amdgcn_mfma_f32_32x32x16_f16(af, bf, acc, 0, 0, 0);
            }
            __syncthreads();  // Xb free (phase2 readers of prev chunk done)
            // epilogue: clip^2 -> Xb (f16, swizzled)
            #pragma unroll
            for (int reg = 0; reg < 16; reg++) {
                int rr = wr * 32 + 4 * kh + (reg & 3) + 8 * (reg >> 2);
                float v = acc[reg];
                v = fminf(fmaxf(v, 0.f), 1.f);
                v = v * v;
                Xb[rr * NCH + ((((colc >> 3) ^ (rr & 7)) << 3) | (colc & 7))] = (f16)v;
            }
            __syncthreads();  // Xb ready

            // ---- phase 2: h1 += act_chunk @ W1_chunk^T (16x16), B-frags from global ----
            const f16x8* w1p = w1fr + ((bkt * 2 + s) * 8 + c) * 512;
            #pragma unroll
            for (int ks = 0; ks < NCH / 32; ks++) {
                int s0 = ks * 4 + l4;
                int row = mt * 16 + l15;
                f16x8 a = *(const f16x8*)(Xb + row * NCH + ((s0 ^ (row & 7)) << 3));
                f16x8 b = w1p[s0 * 32 + nh * 16 + l15];
                h1acc = __builtin_amdgcn_mfma_f32_16x16x32_f16(a, b, h1acc, 0, 0, 0);
            }
        }
    }

    // ---- h1 finalize: clip [0,1] -> h1s (aliases dead Fs) ----
    #pragma unroll
    for (int jr = 0; jr < 4; jr++) {
        int row = mt * 16 + l4 * 4 + jr;
        int col = nh * 16 + l15;
        float v = fminf(fmaxf(h1acc[jr], 0.f), 1.f);
        h1s[row * 40 + col] = (f16)v;
    }
    __syncthreads();

    // ---- layer 3: h2 = clip(h1 @ W2_b^T + b2, 0, 1); W2 frag direct from global ----
    {
        int nn = nh * 16 + l15;
        const float* w2r = W2 + (bkt * 32 + nn) * 32;
        float4 wa = *(const float4*)(w2r + l4 * 8);
        float4 wb = *(const float4*)(w2r + l4 * 8 + 4);
        f16x8 bfr;
        bfr[0]=(f16)wa.x; bfr[1]=(f16)wa.y; bfr[2]=(f16)wa.z; bfr[3]=(f16)wa.w;
        bfr[4]=(f16)wb.x; bfr[5]=(f16)wb.y; bfr[6]=(f16)wb.z; bfr[7]=(f16)wb.w;
        int row = mt * 16 + l15;
        f16x8 a = *(const f16x8*)(h1s + row * 40 + l4 * 8);
        float bb2 = b2[bkt * 32 + nn];
        f32x4 acc2; acc2[0] = acc2[1] = acc2[2] = acc2[3] = bb2;
        acc2 = __builtin_amdgcn_mfma_f32_16x16x32_f16(a, bfr, acc2, 0, 0, 0);
        #pragma unroll
        for (int jr = 0; jr < 4; jr++) {
            int r2 = mt * 16 + l4 * 4 + jr;
            float v = fminf(fmaxf(acc2[jr], 0.f), 1.f);
            h2s[r2 * 40 + nn] = (f16)v;
        }
    }
    __syncthreads();

    // ---- layer 4 + psqt -> output ----
    if (tid < nrows) {
        const float* w3r = W3 + bkt * 32;
        float o = b3[bkt] + psq[tid];
        #pragma unroll 8
        for (int n = 0; n < 32; n++) o += (float)h2s[tid * 40 + n] * w3r[n];
        out[idxl[tid]] = o;
    }
}

// ---------------- launcher ----------------
extern "C" void kernel_launch(void* const* d_in, const int* in_sizes, int n_in,
                              void* d_out, int out_size, void* d_ws, size_t ws_size,
                              hipStream_t stream)
{
    (void)in_sizes; (void)n_in; (void)out_size; (void)ws_size;
    const float* stm  = (const float*)d_in[0];
    const float* nstm = (const float*)d_in[1];
    const float* Wacc = (const float*)d_in[2];
    const float* bacc = (const float*)d_in[3];
    const float* W1   = (const float*)d_in[4];
    const float* b1   = (const float*)d_in[5];
    const float* W2   = (const float*)d_in[6];
    const float* b2   = (const float*)d_in[7];
    const float* W3   = (const float*)d_in[8];
    const float* b3   = (const float*)d_in[9];
    float* out = (float*)d_out;

    char* ws = (char*)d_ws;
    f16* waccF  = (f16*)(ws + WS_WACC16);
    f16* w1F    = (f16*)(ws + WS_W116);
    int* bucket = (int*)(ws + WS_BUCKET);
    int* order  = (int*)(ws + WS_ORDER);
    int* cnt    = (int*)(ws + WS_CNT);
    int* basep  = (int*)(ws + WS_BASE);
    int* part   = (int*)(ws + WS_PART);
    int* bb     = (int*)(ws + WS_BB);
    int* blkmap = (int*)(ws + WS_BLKMAP);   // aliases part (dead after binsetup)

    hipLaunchKernelGGL(k_prep, dim3(1024), dim3(256), 0, stream, Wacc, W1, waccF, w1F);
    hipLaunchKernelGGL(k_bincount, dim3(BINBLK), dim3(512), 0, stream, stm, bucket, part);
    hipLaunchKernelGGL(k_binsetup, dim3(1), dim3(512), 0, stream, part, cnt, basep, bb, blkmap);
    hipLaunchKernelGGL(k_binscatter, dim3(BINBLK), dim3(256), 0, stream, bucket, bb, order);

    hipFuncSetAttribute(reinterpret_cast<const void*>(k_main),
                        hipFuncAttributeMaxDynamicSharedMemorySize, LDS_BYTES);
    hipLaunchKernelGGL(k_main, dim3(MAXBLK), dim3(NT), LDS_BYTES, stream,
                       stm, nstm, Wacc, bacc, b1, W2, b2, W3, b3,
                       waccF, w1F, cnt, basep, order, blkmap, out);
}

// Round 5
// 258.989 us; speedup vs baseline: 3.0560x; 1.0300x over previous
//
#include <hip/hip_runtime.h>

typedef _Float16 f16;
typedef f16 f16x8 __attribute__((ext_vector_type(8)));
typedef float f32x4 __attribute__((ext_vector_type(4)));
typedef float f32x16 __attribute__((ext_vector_type(16)));

#define BATCH   32768
#define NF      162
#define ACCH    1024      // hidden accumulator width (without psqt)
#define KSL     192       // K padded to 192 halfs
#define NKS2    12        // 32x32x16 K-steps per 192
#define NB      8
#define DIVQ    20
#define TM      64        // rows per block
#define NT      512       // threads per block
#define NCH     128       // hidden chunk
#define NCHUNK  (ACCH/NCH) // 8
#define MAXBLK  (BATCH/TM + NB - 1)   // 519

// binning partition
#define BINBLK  256
#define RPB     (BATCH / BINBLK)      // 128 rows per binning block

// workspace layout (bytes)
#define WS_WACC16   0
#define WS_W116     (WS_WACC16 + ACCH*KSL*2)       // 393216
#define WS_BUCKET   (WS_W116 + 256*2048*2)         // 1441792
#define WS_ORDER    (WS_BUCKET + BATCH*4)          // 1572864
#define WS_CNT      (WS_ORDER + BATCH*4)           // 1703936
#define WS_BASE     (WS_CNT + 64)
#define WS_PART     (WS_BASE + 64)                 // BINBLK*8 ints
#define WS_BB       (WS_PART + BINBLK*8*4)         // BINBLK*8 ints
#define WS_BLKMAP   WS_PART                        // reuse: part dead after binsetup reads it

// LDS: Fs 24576 (h1s/h2s alias) + Xb 16384 + psq 256 + idxl 256
#define LDS_BYTES   41472

// ---------------- fused prep + binning ----------------
// blocks [0,256): bucket per row + per-block histogram (no global atomics)
// blocks [256,1024): weights -> f16 fragment-major layouts
// waccF (32x32x16 B-frag): u16 idx = (((c*12+ks)*2 + kh)*128 + n)*8 + e
//   value = Wacc[c*128+n][k], k = ks*16 + kh*8 + e (0 if k>=NF)
// w1F (16x16x32 B-frag): u16 idx = ((((bkt*2+s)*8+c)*16 + ks*4 + l4)*32 + n)*8 + e
//   value = W1[bkt*32+n][s*1024 + c*128 + ks*32 + l4*8 + e]
__global__ __launch_bounds__(512) void k_prepbin(const float* __restrict__ stm,
                                                 const float* __restrict__ Wacc,
                                                 const float* __restrict__ W1,
                                                 int* __restrict__ bucket,
                                                 int* __restrict__ part,
                                                 f16* __restrict__ waccF,
                                                 f16* __restrict__ w1F)
{
    if (blockIdx.x < BINBLK) {
        __shared__ int hist[NB];
        int tid = threadIdx.x;
        if (tid < NB) hist[tid] = 0;
        __syncthreads();
        int wv = tid >> 6, ln = tid & 63;
        int rowbase = blockIdx.x * RPB + wv * (RPB / 8);   // 16 rows per wave
        for (int i = 0; i < RPB / 8; i++) {
            int row = rowbase + i;
            const float* rp = stm + (long)row * NF;
            float s = 0.f;
            for (int k = ln; k < NF; k += 64) s += rp[k];
            for (int off = 32; off > 0; off >>= 1) s += __shfl_down(s, off);
            if (ln == 0) {
                int pc = (int)(s + 0.5f);
                int b = pc / DIVQ; if (b > NB - 1) b = NB - 1;
                bucket[row] = b;
                atomicAdd(&hist[b], 1);
            }
        }
        __syncthreads();
        if (tid < NB) part[blockIdx.x * NB + tid] = hist[tid];
    } else {
        int tid = (blockIdx.x - BINBLK) * blockDim.x + threadIdx.x;
        int stride = (gridDim.x - BINBLK) * blockDim.x;
        for (int t = tid; t < ACCH * KSL; t += stride) {
            int e = t & 7, f = t >> 3;
            int n = f & 127, g = f >> 7;
            int kh = g & 1, h = g >> 1;
            int ks = h % NKS2, c = h / NKS2;
            int k = ks * 16 + kh * 8 + e;
            int row = c * 128 + n;
            waccF[t] = (f16)((k < NF) ? Wacc[row * NF + k] : 0.f);
        }
        for (int t = tid; t < 256 * 2048; t += stride) {
            int e = t & 7, f = t >> 3;
            int n = f & 31, g = f >> 5;
            int l4 = g & 3, h = g >> 2;
            int ks = h & 3, g2 = h >> 2;
            int c = g2 & 7, m = g2 >> 3;
            int s = m & 1, bkt = m >> 1;
            int k = s * ACCH + c * NCH + ks * 32 + l4 * 8 + e;
            w1F[t] = (f16)W1[(bkt * 32 + n) * 2048 + k];
        }
    }
}

// 8 waves, one per bucket: parallel prefix over 256 per-block partials
__global__ __launch_bounds__(512) void k_binsetup(const int* __restrict__ part,
                                                  int* __restrict__ cnt,
                                                  int* __restrict__ base,
                                                  int* __restrict__ bb,
                                                  int* __restrict__ blkmap)
{
    __shared__ int tot[NB], bas[NB], tstart[NB + 1];
    int tid = threadIdx.x;
    int wv = tid >> 6, ln = tid & 63;
    int b = wv;
    int v0 = part[(ln * 4 + 0) * NB + b];
    int v1 = part[(ln * 4 + 1) * NB + b];
    int v2 = part[(ln * 4 + 2) * NB + b];
    int v3 = part[(ln * 4 + 3) * NB + b];
    int s = v0 + v1 + v2 + v3;
    int inc = s;
    for (int off = 1; off < 64; off <<= 1) {
        int n = __shfl_up(inc, off);
        if (ln >= off) inc += n;
    }
    int exc = inc - s;
    if (ln == 63) tot[b] = inc;
    __syncthreads();
    if (tid == 0) {
        int a = 0;
        for (int q = 0; q < NB; q++) { bas[q] = a; base[q] = a; a += tot[q]; }
        int t = 0;
        for (int q = 0; q < NB; q++) { tstart[q] = t; t += (tot[q] + TM - 1) / TM; }
        tstart[NB] = t;
        for (int q = 0; q < NB; q++) cnt[q] = tot[q];
    }
    __syncthreads();
    int run = exc + bas[b];
    bb[(ln * 4 + 0) * NB + b] = run; run += v0;
    bb[(ln * 4 + 1) * NB + b] = run; run += v1;
    bb[(ln * 4 + 2) * NB + b] = run; run += v2;
    bb[(ln * 4 + 3) * NB + b] = run;
    for (int i = tid; i < MAXBLK; i += 512) {
        int v = -1;
        for (int q = 0; q < NB; q++)
            if (i >= tstart[q] && i < tstart[q + 1]) v = q | ((i - tstart[q]) << 4);
        blkmap[i] = v;
    }
}

__global__ __launch_bounds__(256) void k_binscatter(const int* __restrict__ bucket,
                                                    const int* __restrict__ bb,
                                                    int* __restrict__ order)
{
    __shared__ int lcur[NB];
    int tid = threadIdx.x;
    if (tid < NB) lcur[tid] = bb[blockIdx.x * NB + tid];
    __syncthreads();
    int blkstart = blockIdx.x * RPB;
    for (int i = tid; i < RPB; i += 256) {
        int row = blkstart + i;
        int b = bucket[row];
        int pos = atomicAdd(&lcur[b], 1);
        order[pos] = row;
    }
}

// ---------------- fused main kernel ----------------
__global__ __launch_bounds__(NT, 5) void k_main(
    const float* __restrict__ stm, const float* __restrict__ nstm,
    const float* __restrict__ Wacc, const float* __restrict__ bacc,
    const float* __restrict__ b1, const float* __restrict__ W2,
    const float* __restrict__ b2, const float* __restrict__ W3,
    const float* __restrict__ b3,
    const f16* __restrict__ waccF, const f16* __restrict__ w1F,
    const int* __restrict__ cnt, const int* __restrict__ base,
    const int* __restrict__ order, const int* __restrict__ blkmap,
    float* __restrict__ out)
{
    int bm = blkmap[blockIdx.x];
    if (bm < 0) return;
    int bkt = bm & 15, tile = bm >> 4;
    int rowbase = base[bkt] + tile * TM;
    int nrows = cnt[bkt] - tile * TM; if (nrows > TM) nrows = TM;

    extern __shared__ __align__(16) char lds_raw[];
    f16* Fs   = (f16*)lds_raw;                         // [64][192] swizzled
    f16* Xb   = (f16*)(lds_raw + TM * KSL * 2);        // [64][128] swizzled (single buffer)
    float* psq  = (float*)(lds_raw + TM * KSL * 2 + TM * NCH * 2);   // [64]
    int*   idxl = (int*)((char*)psq + TM * 4);                       // [64]
    f16* h1s  = (f16*)lds_raw;                         // [64][40], aliases Fs (dead)
    f16* h2s  = (f16*)(lds_raw + TM * 40 * 2);         // [64][40], aliases Fs

    int tid = threadIdx.x;
    int wv = tid >> 6, ln = tid & 63;
    int l15 = ln & 15, l4 = ln >> 4;
    int col31 = ln & 31, kh = ln >> 5;

    if (tid < TM) {
        int rr = rowbase + tid;
        idxl[tid] = order[(tid < nrows) ? rr : rowbase];
    }
    __syncthreads();

    // wave tile assignment
    int wr = wv & 1;    // phase1 row-half
    int wc = wv >> 1;   // phase1 col-quarter
    int mt = wv >> 1;   // phase2/3: M-tile 0..3
    int nh = wv & 1;    // phase2/3: N-half 0..1

    int arow = wr * 32 + col31;
    int axor = arow & 7;
    int colc = wc * 32 + col31;   // col within chunk (0..127)

    float bb1 = b1[bkt * 32 + nh * 16 + l15];
    f32x4 h1acc; h1acc[0] = h1acc[1] = h1acc[2] = h1acc[3] = bb1;

    const float* psqw = Wacc + (long)ACCH * NF;   // psqt weight row (fp32)
    const f16x8* wfr  = (const f16x8*)waccF;
    const f16x8* w1fr = (const f16x8*)w1F;

    int rloc = ln >> 3, j = ln & 7;
    int srow = wv * 8 + rloc;            // staging row owned by this lane
    int sxor = srow & 7;

    for (int s = 0; s < 2; s++) {
        const float* src = s ? nstm : stm;
        // ---- fused feature staging + psqt (vectorized, ds_write_b128) ----
        {
            const float* rp = src + (long)idxl[srow] * NF;
            float pp = 0.f;
            #pragma unroll
            for (int bq = 0; bq < 3; bq++) {
                int slot = j + bq * 8;
                int k0 = slot * 8;
                float f0=0.f,f1=0.f,f2=0.f,f3=0.f,f4=0.f,f5=0.f,f6=0.f,f7=0.f;
                if (slot < 20) {
                    float2 a0 = *(const float2*)(rp + k0);
                    float2 a1 = *(const float2*)(rp + k0 + 2);
                    float2 a2 = *(const float2*)(rp + k0 + 4);
                    float2 a3 = *(const float2*)(rp + k0 + 6);
                    f0=a0.x; f1=a0.y; f2=a1.x; f3=a1.y;
                    f4=a2.x; f5=a2.y; f6=a3.x; f7=a3.y;
                    pp += f0*psqw[k0]   + f1*psqw[k0+1] + f2*psqw[k0+2] + f3*psqw[k0+3]
                        + f4*psqw[k0+4] + f5*psqw[k0+5] + f6*psqw[k0+6] + f7*psqw[k0+7];
                } else if (slot == 20) {
                    float2 a0 = *(const float2*)(rp + 160);
                    f0 = a0.x; f1 = a0.y;
                    pp += f0*psqw[160] + f1*psqw[161];
                }
                f16x8 h;
                h[0]=(f16)f0; h[1]=(f16)f1; h[2]=(f16)f2; h[3]=(f16)f3;
                h[4]=(f16)f4; h[5]=(f16)f5; h[6]=(f16)f6; h[7]=(f16)f7;
                *(f16x8*)(Fs + srow * KSL + ((slot ^ sxor) << 3)) = h;
            }
            pp += __shfl_xor(pp, 1);
            pp += __shfl_xor(pp, 2);
            pp += __shfl_xor(pp, 4);
            if (j == 0) {
                if (s) psq[srow] -= 0.5f * pp;
                else   psq[srow]  = 0.5f * pp;
            }
        }
        __syncthreads();  // Fs ready

        for (int c = 0; c < NCHUNK; c++) {
            // ---- phase 1: 32x32 MFMA, wave = rows [wr*32,+32) x cols [wc*32,+32) ----
            float bias = bacc[c * NCH + colc];
            f32x16 acc;
            #pragma unroll
            for (int q = 0; q < 16; q++) acc[q] = bias;

            #pragma unroll
            for (int ks = 0; ks < NKS2; ks++) {
                f16x8 bf = wfr[((c * NKS2 + ks) * 2 + kh) * 128 + colc];
                int slot = ks * 2 + kh;
                f16x8 af = *(const f16x8*)(Fs + arow * KSL + ((slot ^ axor) << 3));
                acc = __builtin_amdgcn_mfma_f32_32x32x16_f16(af, bf, acc, 0, 0, 0);
            }
            __syncthreads();  // Xb free (phase2 readers of prev chunk done)
            // epilogue: clip^2 -> Xb (f16, swizzled)
            #pragma unroll
            for (int reg = 0; reg < 16; reg++) {
                int rr = wr * 32 + 4 * kh + (reg & 3) + 8 * (reg >> 2);
                float v = acc[reg];
                v = fminf(fmaxf(v, 0.f), 1.f);
                v = v * v;
                Xb[rr * NCH + ((((colc >> 3) ^ (rr & 7)) << 3) | (colc & 7))] = (f16)v;
            }
            __syncthreads();  // Xb ready

            // ---- phase 2: h1 += act_chunk @ W1_chunk^T (16x16), B-frags from global ----
            const f16x8* w1p = w1fr + ((bkt * 2 + s) * 8 + c) * 512;
            #pragma unroll
            for (int ks = 0; ks < NCH / 32; ks++) {
                int s0 = ks * 4 + l4;
                int row = mt * 16 + l15;
                f16x8 a = *(const f16x8*)(Xb + row * NCH + ((s0 ^ (row & 7)) << 3));
                f16x8 b = w1p[s0 * 32 + nh * 16 + l15];
                h1acc = __builtin_amdgcn_mfma_f32_16x16x32_f16(a, b, h1acc, 0, 0, 0);
            }
        }
    }

    // ---- h1 finalize: clip [0,1] -> h1s (aliases dead Fs) ----
    #pragma unroll
    for (int jr = 0; jr < 4; jr++) {
        int row = mt * 16 + l4 * 4 + jr;
        int col = nh * 16 + l15;
        float v = fminf(fmaxf(h1acc[jr], 0.f), 1.f);
        h1s[row * 40 + col] = (f16)v;
    }
    __syncthreads();

    // ---- layer 3: h2 = clip(h1 @ W2_b^T + b2, 0, 1); W2 frag direct from global ----
    {
        int nn = nh * 16 + l15;
        const float* w2r = W2 + (bkt * 32 + nn) * 32;
        float4 wa = *(const float4*)(w2r + l4 * 8);
        float4 wb = *(const float4*)(w2r + l4 * 8 + 4);
        f16x8 bfr;
        bfr[0]=(f16)wa.x; bfr[1]=(f16)wa.y; bfr[2]=(f16)wa.z; bfr[3]=(f16)wa.w;
        bfr[4]=(f16)wb.x; bfr[5]=(f16)wb.y; bfr[6]=(f16)wb.z; bfr[7]=(f16)wb.w;
        int row = mt * 16 + l15;
        f16x8 a = *(const f16x8*)(h1s + row * 40 + l4 * 8);
        float bb2 = b2[bkt * 32 + nn];
        f32x4 acc2; acc2[0] = acc2[1] = acc2[2] = acc2[3] = bb2;
        acc2 = __builtin_amdgcn_mfma_f32_16x16x32_f16(a, bfr, acc2, 0, 0, 0);
        #pragma unroll
        for (int jr = 0; jr < 4; jr++) {
            int r2 = mt * 16 + l4 * 4 + jr;
            float v = fminf(fmaxf(acc2[jr], 0.f), 1.f);
            h2s[r2 * 40 + nn] = (f16)v;
        }
    }
    __syncthreads();

    // ---- layer 4 + psqt -> output ----
    if (tid < nrows) {
        const float* w3r = W3 + bkt * 32;
        float o = b3[bkt] + psq[tid];
        #pragma unroll 8
        for (int n = 0; n < 32; n++) o += (float)h2s[tid * 40 + n] * w3r[n];
        out[idxl[tid]] = o;
    }
}

// ---------------- launcher ----------------
extern "C" void kernel_launch(void* const* d_in, const int* in_sizes, int n_in,
                              void* d_out, int out_size, void* d_ws, size_t ws_size,
                              hipStream_t stream)
{
    (void)in_sizes; (void)n_in; (void)out_size; (void)ws_size;
    const float* stm  = (const float*)d_in[0];
    const float* nstm = (const float*)d_in[1];
    const float* Wacc = (const float*)d_in[2];
    const float* bacc = (const float*)d_in[3];
    const float* W1   = (const float*)d_in[4];
    const float* b1   = (const float*)d_in[5];
    const float* W2   = (const float*)d_in[6];
    const float* b2   = (const float*)d_in[7];
    const float* W3   = (const float*)d_in[8];
    const float* b3   = (const float*)d_in[9];
    float* out = (float*)d_out;

    char* ws = (char*)d_ws;
    f16* waccF  = (f16*)(ws + WS_WACC16);
    f16* w1F    = (f16*)(ws + WS_W116);
    int* bucket = (int*)(ws + WS_BUCKET);
    int* order  = (int*)(ws + WS_ORDER);
    int* cnt    = (int*)(ws + WS_CNT);
    int* basep  = (int*)(ws + WS_BASE);
    int* part   = (int*)(ws + WS_PART);
    int* bb     = (int*)(ws + WS_BB);
    int* blkmap = (int*)(ws + WS_BLKMAP);   // aliases part (dead after binsetup)

    hipLaunchKernelGGL(k_prepbin, dim3(1024), dim3(512), 0, stream,
                       stm, Wacc, W1, bucket, part, waccF, w1F);
    hipLaunchKernelGGL(k_binsetup, dim3(1), dim3(512), 0, stream, part, cnt, basep, bb, blkmap);
    hipLaunchKernelGGL(k_binscatter, dim3(BINBLK), dim3(256), 0, stream, bucket, bb, order);

    hipFuncSetAttribute(reinterpret_cast<const void*>(k_main),
                        hipFuncAttributeMaxDynamicSharedMemorySize, LDS_BYTES);
    hipLaunchKernelGGL(k_main, dim3(MAXBLK), dim3(NT), LDS_BYTES, stream,
                       stm, nstm, Wacc, bacc, b1, W2, b2, W3, b3,
                       waccF, w1F, cnt, basep, order, blkmap, out);
}